// Round 1
// baseline (264.935 us; speedup 1.0000x reference)
//
#include <hip/hip_runtime.h>

// SpanNER decomposition:
//   span[b,k] = hidden[b,si]@A_s + hidden[b,ei]@A_e + (width_emb[w]@A_w + b_span)
//   where A_s = w_span[0:768], A_e = w_span[768:1536], A_w = w_span[1536:2304]
//   logits = span . w_cls + b_cls      (decomposes into per-position scalars)
//   proj   = relu(span@w_p1 + b_p1)@w_p2 + b_p2   (span@w_p1 decomposes likewise)
// Pad rows (k >= 765) are a single constant logit + constant 128-vector.

#define D 768
#define BATCH 2
#define S 256
#define TOTAL 32896      // S*(S+1)/2
#define NVALID 765
#define NPADROW (TOTAL - NVALID)   // 32131
#define PD 128
#define LOGITS_SZ (BATCH * TOTAL)  // 65792

// workspace offsets (in floats)
#define WS_H    0               // [2][512][768]  H1,H2 = hidden @ A_s / A_e
#define WS_P1   786432          // [2][512][768]  P1s,P1e = H @ w_p1
#define WS_WE3  1572864         // [3][768]       width_emb@A_w + b_span
#define WS_P1W  1575168         // [3][768]       WE3@w_p1 + b_p1
#define WS_TPAD 1577472         // [768]          relu(b_span@w_p1 + b_p1)
#define WS_L    1578240         // [2][512]       H . w_cls
#define WS_LW   1579264         // [3]            WE3 . w_cls + b_cls
#define WS_LPAD 1579267         // [1]            pad logit
#define WS_PPAD 1579268         // [128]          pad proj vector

__device__ __forceinline__ void span_iw(int k, int& i, int& w) {
    if (k < 762)      { i = k / 3;  w = k - i * 3; }
    else if (k < 764) { i = 254;    w = k - 762; }
    else              { i = 255;    w = 0; }
}

// ---- K0: width-embedding projections + pad constants (indep. of hidden) ----
__global__ void k_prep1(const float* __restrict__ width_emb, const float* __restrict__ w_span,
                        const float* __restrict__ b_span, const float* __restrict__ w_cls,
                        const float* __restrict__ b_cls, const float* __restrict__ w_p1,
                        const float* __restrict__ b_p1, float* __restrict__ ws) {
    int idx = blockIdx.x * 256 + threadIdx.x;
    if (idx < 3 * D) {
        int w = idx / D, d = idx - w * D;
        float acc = b_span[d];
        const float* wsp = w_span + 2 * D * D + d;   // A_w column d
        for (int k = 0; k < D; ++k) acc = fmaf(width_emb[w * D + k], wsp[k * D], acc);
        ws[WS_WE3 + idx] = acc;
    } else if (idx < 4 * D) {
        int d = idx - 3 * D;
        float acc = b_p1[d];
        for (int k = 0; k < D; ++k) acc = fmaf(b_span[k], w_p1[k * D + d], acc);
        ws[WS_TPAD + d] = fmaxf(acc, 0.f);
    } else if (idx == 4 * D) {
        float acc = b_cls[0];
        for (int k = 0; k < D; ++k) acc = fmaf(b_span[k], w_cls[k], acc);
        ws[WS_LPAD] = acc;
    }
}

// ---- fp32 tiled GEMM: C[g](512x768) = A[g](512x768) @ B[g](768x768) ----
// grid (8,12,2), 256 threads, 64x64 tile, BK=16, 4x4 microtile, reg prefetch.
__global__ __launch_bounds__(256) void k_gemm(const float* __restrict__ Abase,
                                              const float* __restrict__ Bbase,
                                              float* __restrict__ Cbase,
                                              int aStride, int bStride) {
    const int g = blockIdx.z;
    const float* A = Abase + (size_t)g * aStride;
    const float* Bm = Bbase + (size_t)g * bStride;
    float* C = Cbase + (size_t)g * (512 * D);
    const int m0 = blockIdx.x * 64, n0 = blockIdx.y * 64;
    const int tid = threadIdx.x;
    __shared__ __align__(16) float As[16][64];   // [k][m]
    __shared__ __align__(16) float Bs[16][64];   // [k][n]
    const int arow = tid >> 2, akq = (tid & 3) << 2;        // A: 64 rows x 4 k-quads
    const int bkr = tid >> 4, bjq = (tid & 15) << 2;        // B: 16 k-rows x 16 j-quads
    const int crq = (tid >> 4) << 2, ccq = (tid & 15) << 2; // C microtile origin
    float acc[4][4] = {};
    float4 av = *(const float4*)&A[(m0 + arow) * D + akq];
    float4 bv = *(const float4*)&Bm[bkr * D + n0 + bjq];
    for (int kt = 0; kt < D / 16; ++kt) {
        As[akq + 0][arow] = av.x; As[akq + 1][arow] = av.y;
        As[akq + 2][arow] = av.z; As[akq + 3][arow] = av.w;
        *(float4*)&Bs[bkr][bjq] = bv;
        __syncthreads();
        if (kt + 1 < D / 16) {
            av = *(const float4*)&A[(m0 + arow) * D + (kt + 1) * 16 + akq];
            bv = *(const float4*)&Bm[((kt + 1) * 16 + bkr) * D + n0 + bjq];
        }
        #pragma unroll
        for (int k = 0; k < 16; ++k) {
            float4 a4 = *(const float4*)&As[k][crq];
            float4 b4 = *(const float4*)&Bs[k][ccq];
            float ar[4] = {a4.x, a4.y, a4.z, a4.w};
            float br[4] = {b4.x, b4.y, b4.z, b4.w};
            #pragma unroll
            for (int i = 0; i < 4; ++i)
                #pragma unroll
                for (int j = 0; j < 4; ++j)
                    acc[i][j] = fmaf(ar[i], br[j], acc[i][j]);
        }
        __syncthreads();
    }
    #pragma unroll
    for (int i = 0; i < 4; ++i) {
        float4 o = make_float4(acc[i][0], acc[i][1], acc[i][2], acc[i][3]);
        *(float4*)&C[(size_t)(m0 + crq + i) * D + n0 + ccq] = o;
    }
}

// ---- K2b: logit vectors L = H.w_cls (wave/row), P1w, Lw, proj_pad ----
__global__ void k_prep2(const float* __restrict__ w_cls, const float* __restrict__ b_cls,
                        const float* __restrict__ w_p1, const float* __restrict__ b_p1,
                        const float* __restrict__ w_p2, const float* __restrict__ b_p2,
                        float* __restrict__ ws) {
    const int bx = blockIdx.x, tid = threadIdx.x;
    if (bx < 256) {                       // L: 1024 rows, wave per row
        int r = bx * 4 + (tid >> 6);
        int lane = tid & 63;
        const float* Hrow = ws + WS_H + (size_t)r * D;
        float acc = 0.f;
        for (int d = lane; d < D; d += 64) acc = fmaf(Hrow[d], w_cls[d], acc);
        for (int off = 32; off > 0; off >>= 1) acc += __shfl_down(acc, off, 64);
        if (lane == 0) ws[WS_L + r] = acc;
    } else if (bx < 265) {                // P1w: 3x768
        int idx = (bx - 256) * 256 + tid;
        int w = idx / D, d = idx - w * D;
        float acc = b_p1[d];
        const float* we = ws + WS_WE3 + w * D;
        for (int k = 0; k < D; ++k) acc = fmaf(we[k], w_p1[k * D + d], acc);
        ws[WS_P1W + idx] = acc;
    } else {                              // Lw (3) + proj_pad (128)
        if (tid < 3) {
            float acc = b_cls[0];
            const float* we = ws + WS_WE3 + tid * D;
            for (int k = 0; k < D; ++k) acc = fmaf(we[k], w_cls[k], acc);
            ws[WS_LW + tid] = acc;
        } else if (tid >= 64 && tid < 192) {
            int jj = tid - 64;
            float acc = b_p2[jj];
            const float* tp = ws + WS_TPAD;
            for (int k = 0; k < D; ++k) acc = fmaf(tp[k], w_p2[k * PD + jj], acc);
            ws[WS_PPAD + jj] = acc;
        }
    }
}

// ---- K3: span epilogue (blocks 0..191) + pad fill (blocks 192..1215) ----
__global__ __launch_bounds__(256) void k_span_fill(const float* __restrict__ w_p2,
                                                   const float* __restrict__ b_p2,
                                                   const float* __restrict__ ws,
                                                   float* __restrict__ out) {
    const int tid = threadIdx.x;
    if (blockIdx.x < 192) {
        const int b = blockIdx.x / 96;
        const int s0 = (blockIdx.x % 96) * 8;
        const int cnt = min(8, NVALID - s0);
        __shared__ float tld[8 * 772];    // padded stride: banks (4s+d)%32 distinct
        const float* P1 = ws + WS_P1;
        const float* P1w = ws + WS_P1W;
        for (int e = tid; e < 8 * D; e += 256) {      // t = relu(P1s+P1e+P1w)
            int s = e / D;
            if (s >= cnt) break;
            int d = e - s * D, k = s0 + s, i, w;
            span_iw(k, i, w);
            int j = i + w;
            float v = P1[(size_t)(b * S + i) * D + d]
                    + P1[(size_t)(512 + b * S + j) * D + d]
                    + P1w[w * D + d];
            tld[s * 772 + d] = fmaxf(v, 0.f);
        }
        if (tid < cnt) {                              // logits for these spans
            int k = s0 + tid, i, w;
            span_iw(k, i, w);
            int j = i + w;
            out[b * TOTAL + k] = ws[WS_L + b * S + i] + ws[WS_L + 512 + b * S + j]
                               + ws[WS_LW + w];
        }
        __syncthreads();
        int s = tid >> 5;                              // proj = t @ w_p2 + b_p2
        if (s < cnt) {
            int j4 = (tid & 31) << 2;
            float4 acc = *(const float4*)&b_p2[j4];
            const float4* wp2 = (const float4*)w_p2;
            const float* trow = &tld[s * 772];
            #pragma unroll 4
            for (int d = 0; d < D; ++d) {
                float tv = trow[d];
                float4 wv = wp2[d * (PD / 4) + (tid & 31)];
                acc.x = fmaf(tv, wv.x, acc.x);
                acc.y = fmaf(tv, wv.y, acc.y);
                acc.z = fmaf(tv, wv.z, acc.z);
                acc.w = fmaf(tv, wv.w, acc.w);
            }
            *(float4*)&out[LOGITS_SZ + ((size_t)b * TOTAL + s0 + s) * PD + j4] = acc;
        }
    } else {
        // constant fill of pad logits + pad proj rows (33 MB, BW-bound)
        const int ft = (blockIdx.x - 192) * 256 + tid;     // [0, 262144)
        if (ft < BATCH * NPADROW) {
            int b = ft / NPADROW;
            int k = NVALID + (ft - b * NPADROW);
            out[b * TOTAL + k] = ws[WS_LPAD];
        }
        float4 pp = *(const float4*)&ws[WS_PPAD + ((ft & 31) << 2)];
        float4* outp4 = (float4*)(out + LOGITS_SZ);
        const long long totalU = (long long)BATCH * NPADROW * 32;  // 2056384 float4s
        for (long long u = ft; u < totalU; u += 262144) {
            int rb = (int)(u >> 5);
            int b = rb / NPADROW;
            int k = NVALID + (rb - b * NPADROW);
            outp4[((size_t)b * TOTAL + k) * 32 + (u & 31)] = pp;
        }
    }
}

extern "C" void kernel_launch(void* const* d_in, const int* in_sizes, int n_in,
                              void* d_out, int out_size, void* d_ws, size_t ws_size,
                              hipStream_t stream) {
    const float* hidden    = (const float*)d_in[0];
    const float* width_emb = (const float*)d_in[1];
    const float* w_span    = (const float*)d_in[2];
    const float* b_span    = (const float*)d_in[3];
    const float* w_cls     = (const float*)d_in[4];
    const float* b_cls     = (const float*)d_in[5];
    const float* w_p1      = (const float*)d_in[6];
    const float* b_p1      = (const float*)d_in[7];
    const float* w_p2      = (const float*)d_in[8];
    const float* b_p2      = (const float*)d_in[9];
    float* out = (float*)d_out;
    float* ws  = (float*)d_ws;   // needs ~6.04 MB

    k_prep1<<<13, 256, 0, stream>>>(width_emb, w_span, b_span, w_cls, b_cls, w_p1, b_p1, ws);
    // H1,H2 = hidden @ A_s / A_e   (A shared, B strided by 768 rows)
    k_gemm<<<dim3(8, 12, 2), 256, 0, stream>>>(hidden, w_span, ws + WS_H, 0, D * D);
    // P1s,P1e = H @ w_p1           (A strided, B shared)
    k_gemm<<<dim3(8, 12, 2), 256, 0, stream>>>(ws + WS_H, w_p1, ws + WS_P1, 512 * D, 0);
    k_prep2<<<266, 256, 0, stream>>>(w_cls, b_cls, w_p1, b_p1, w_p2, b_p2, ws);
    k_span_fill<<<192 + 1024, 256, 0, stream>>>(w_p2, b_p2, ws, out);
}

// Round 2
// 246.575 us; speedup vs baseline: 1.0745x; 1.0745x over previous
//
#include <hip/hip_runtime.h>

// SpanNER decomposition (fp32, latency-optimized):
//   H[0:512]   = hidden @ A_s        (GEMM1, K-split 2, atomic accum)
//   H[512:1024]= hidden @ A_e
//   H[1024:1027]= WE3 = width_emb @ A_w + b_span          (prepA)
//   P1[0:1027] = H @ w_p1            (GEMM2, K-split 2, atomic accum; rows 1024+ = P1W raw)
//   L[r] = H[r].w_cls                (prepB)
//   span t = relu(P1[si]+P1[ei]+P1[1024+w]+b_p1);  proj = t@w_p2+b_p2  (k_span)
//   pad rows: constant logit + constant 128-vec     (fill, fused into GEMM2 grid)

#define D 768
#define S 256
#define TOTAL 32896
#define NVALID 765
#define NPADROW (TOTAL - NVALID)      // 32131
#define PD 128
#define LOGITS_SZ (2 * TOTAL)         // 65792

// workspace layout (floats)
#define WS_H    0                     // [1027][768]
#define WS_P1   788736                // [1027][768]
#define WS_TPAD 1577472               // [768]
#define WS_L    1578240               // [1024]
#define WS_LW   1579264               // [3]
#define WS_LPAD 1579267               // [1]
#define WS_PPAD 1579268               // [128]  (16B aligned)
#define WS_ZERO_BYTES (WS_TPAD * 4)   // zero H + P1 regions

__device__ __forceinline__ void span_iw(int k, int& i, int& w) {
    if (k < 762)      { i = k / 3;  w = k - i * 3; }
    else if (k < 764) { i = 254;    w = k - 762; }
    else              { i = 255;    w = 0; }
}

// ---- prepA: WE3 (-> H rows 1024..1026), TPAD, LPAD.  grid 49 x 256 ----
__global__ __launch_bounds__(256) void k_prepA(const float* __restrict__ width_emb,
                                               const float* __restrict__ w_span,
                                               const float* __restrict__ b_span,
                                               const float* __restrict__ w_cls,
                                               const float* __restrict__ b_cls,
                                               const float* __restrict__ w_p1,
                                               const float* __restrict__ b_p1,
                                               float* __restrict__ ws) {
    const int bx = blockIdx.x, tid = threadIdx.x;
    const int kc = tid >> 6, dl = tid & 63;        // K-chunk (4) x output lane (64)
    __shared__ float red[256];
    if (bx < 36) {                                  // WE3[w][d] = width_emb[w]@A_w + b_span
        const int w = bx / 12, d = (bx % 12) * 64 + dl;
        const float* wk = w_span + (size_t)(2 * D) * D + d;   // A_w column d
        const float* we = width_emb + w * D;
        float p = 0.f;
        #pragma unroll 4
        for (int k = kc * 192; k < kc * 192 + 192; ++k)
            p = fmaf(we[k], wk[(size_t)k * D], p);
        red[tid] = p; __syncthreads();
        if (kc == 0) {
            float s = red[dl] + red[64 + dl] + red[128 + dl] + red[192 + dl] + b_span[d];
            ws[WS_H + (size_t)(1024 + w) * D + d] = s;
        }
    } else if (bx < 48) {                           // TPAD = relu(b_span@w_p1 + b_p1)
        const int d = (bx - 36) * 64 + dl;
        float p = 0.f;
        #pragma unroll 4
        for (int k = kc * 192; k < kc * 192 + 192; ++k)
            p = fmaf(b_span[k], w_p1[(size_t)k * D + d], p);
        red[tid] = p; __syncthreads();
        if (kc == 0) {
            float s = red[dl] + red[64 + dl] + red[128 + dl] + red[192 + dl] + b_p1[d];
            ws[WS_TPAD + d] = fmaxf(s, 0.f);
        }
    } else {                                        // LPAD = b_span.w_cls + b_cls
        if (tid < 64) {
            float a = 0.f;
            for (int k = tid; k < D; k += 64) a = fmaf(b_span[k], w_cls[k], a);
            for (int off = 32; off > 0; off >>= 1) a += __shfl_down(a, off, 64);
            if (tid == 0) ws[WS_LPAD] = a + b_cls[0];
        }
    }
}

// ---- GEMM1: H[g2*512 + r][n] += hidden @ [A_s|A_e], K-split 2, atomic ----
// grid (8, 24, 2), 256 threads, 64x64 tile, BK=16, 4x4 microtile
__global__ __launch_bounds__(256) void k_gemm1(const float* __restrict__ hidden,
                                               const float* __restrict__ w_span,
                                               float* __restrict__ ws) {
    const int m0 = blockIdx.x * 64;
    const int ng = blockIdx.y * 64;
    const int g2 = ng >= D;
    const int n0 = ng - g2 * D;
    const int k0 = blockIdx.z * 384;
    const float* B = w_span + (size_t)g2 * D * D;
    const int tid = threadIdx.x;
    __shared__ __align__(16) float As[16][64];
    __shared__ __align__(16) float Bs[16][64];
    const int arow = tid >> 2, akq = (tid & 3) << 2;
    const int bkr = tid >> 4, bjq = (tid & 15) << 2;
    const int crq = (tid >> 4) << 2, ccq = (tid & 15) << 2;
    const size_t aBase = (size_t)(m0 + arow) * D + k0;
    float acc[4][4] = {};
    float4 av = *(const float4*)&hidden[aBase + akq];
    float4 bv = *(const float4*)&B[(size_t)(k0 + bkr) * D + n0 + bjq];
    for (int kt = 0; kt < 24; ++kt) {
        As[akq + 0][arow] = av.x; As[akq + 1][arow] = av.y;
        As[akq + 2][arow] = av.z; As[akq + 3][arow] = av.w;
        *(float4*)&Bs[bkr][bjq] = bv;
        __syncthreads();
        if (kt + 1 < 24) {
            av = *(const float4*)&hidden[aBase + (kt + 1) * 16 + akq];
            bv = *(const float4*)&B[(size_t)(k0 + (kt + 1) * 16 + bkr) * D + n0 + bjq];
        }
        #pragma unroll
        for (int k = 0; k < 16; ++k) {
            float4 a4 = *(const float4*)&As[k][crq];
            float4 b4 = *(const float4*)&Bs[k][ccq];
            float ar[4] = {a4.x, a4.y, a4.z, a4.w};
            float br[4] = {b4.x, b4.y, b4.z, b4.w};
            #pragma unroll
            for (int i = 0; i < 4; ++i)
                #pragma unroll
                for (int j = 0; j < 4; ++j)
                    acc[i][j] = fmaf(ar[i], br[j], acc[i][j]);
        }
        __syncthreads();
    }
    float* C = ws + WS_H;
    #pragma unroll
    for (int i = 0; i < 4; ++i)
        #pragma unroll
        for (int j = 0; j < 4; ++j)
            atomicAdd(&C[(size_t)(g2 * 512 + m0 + crq + i) * D + n0 + ccq + j], acc[i][j]);
}

// ---- prepB: L (1024 dots), LW (3), PPAD (128).  grid 258 x 256 ----
__global__ __launch_bounds__(256) void k_prepB(const float* __restrict__ w_cls,
                                               const float* __restrict__ b_cls,
                                               const float* __restrict__ w_p2,
                                               const float* __restrict__ b_p2,
                                               float* __restrict__ ws) {
    const int bx = blockIdx.x, tid = threadIdx.x;
    if (bx < 256) {                                 // L[r] = H[r].w_cls
        const int r = bx * 4 + (tid >> 6), lane = tid & 63;
        const float* Hr = ws + WS_H + (size_t)r * D;
        float a = 0.f;
        for (int d = lane; d < D; d += 64) a = fmaf(Hr[d], w_cls[d], a);
        for (int off = 32; off > 0; off >>= 1) a += __shfl_down(a, off, 64);
        if (lane == 0) ws[WS_L + r] = a;
    } else if (bx == 256) {                         // LW[w] = WE3[w].w_cls + b_cls
        const int wid = tid >> 6, lane = tid & 63;
        if (wid < 3) {
            const float* Hr = ws + WS_H + (size_t)(1024 + wid) * D;
            float a = 0.f;
            for (int d = lane; d < D; d += 64) a = fmaf(Hr[d], w_cls[d], a);
            for (int off = 32; off > 0; off >>= 1) a += __shfl_down(a, off, 64);
            if (lane == 0) ws[WS_LW + wid] = a + b_cls[0];
        }
    } else {                                        // PPAD = TPAD@w_p2 + b_p2
        const int j = tid & 127, h = tid >> 7;
        __shared__ float red[128];
        float a = 0.f;
        #pragma unroll 4
        for (int d = h * 384; d < h * 384 + 384; ++d)
            a = fmaf(ws[WS_TPAD + d], w_p2[(size_t)d * PD + j], a);
        if (h) red[j] = a;
        __syncthreads();
        if (!h) ws[WS_PPAD + j] = a + red[j] + b_p2[j];
    }
}

// ---- GEMM2 (blocks 0..407) + pad fill (blocks 408..919) ----
__global__ __launch_bounds__(256) void k_gemm2_fill(const float* __restrict__ w_p1,
                                                    float* __restrict__ ws,
                                                    float* __restrict__ out) {
    const int bid = blockIdx.x, tid = threadIdx.x;
    if (bid < 408) {
        const int z = bid & 1, t = bid >> 1;
        const int nt = t % 12, mt = t / 12;         // mt 0..16
        const int m0 = mt * 64, n0 = nt * 64, k0 = z * 384;
        __shared__ __align__(16) float As[16][64];
        __shared__ __align__(16) float Bs[16][64];
        const int arow = tid >> 2, akq = (tid & 3) << 2;
        const int bkr = tid >> 4, bjq = (tid & 15) << 2;
        const int crq = (tid >> 4) << 2, ccq = (tid & 15) << 2;
        int ar = m0 + arow; if (ar > 1026) ar = 1026;   // clamp reads into valid H
        const float* A = ws + WS_H;
        const size_t aBase = (size_t)ar * D + k0;
        float acc[4][4] = {};
        float4 av = *(const float4*)&A[aBase + akq];
        float4 bv = *(const float4*)&w_p1[(size_t)(k0 + bkr) * D + n0 + bjq];
        for (int kt = 0; kt < 24; ++kt) {
            As[akq + 0][arow] = av.x; As[akq + 1][arow] = av.y;
            As[akq + 2][arow] = av.z; As[akq + 3][arow] = av.w;
            *(float4*)&Bs[bkr][bjq] = bv;
            __syncthreads();
            if (kt + 1 < 24) {
                av = *(const float4*)&A[aBase + (kt + 1) * 16 + akq];
                bv = *(const float4*)&w_p1[(size_t)(k0 + (kt + 1) * 16 + bkr) * D + n0 + bjq];
            }
            #pragma unroll
            for (int k = 0; k < 16; ++k) {
                float4 a4 = *(const float4*)&As[k][crq];
                float4 b4 = *(const float4*)&Bs[k][ccq];
                float arr[4] = {a4.x, a4.y, a4.z, a4.w};
                float br[4]  = {b4.x, b4.y, b4.z, b4.w};
                #pragma unroll
                for (int i = 0; i < 4; ++i)
                    #pragma unroll
                    for (int j = 0; j < 4; ++j)
                        acc[i][j] = fmaf(arr[i], br[j], acc[i][j]);
            }
            __syncthreads();
        }
        float* C = ws + WS_P1;
        #pragma unroll
        for (int i = 0; i < 4; ++i) {
            const int row = m0 + crq + i;
            if (row < 1027) {
                #pragma unroll
                for (int j = 0; j < 4; ++j)
                    atomicAdd(&C[(size_t)row * D + n0 + ccq + j], acc[i][j]);
            }
        }
    } else {
        // constant pad fill: logits (64262 scalars) + proj rows (33 MB)
        const int fb = bid - 408;
        const int t0 = fb * 256 + tid;              // 0..131071
        if (t0 < 2 * NPADROW) {
            int b = t0 / NPADROW;
            out[b * TOTAL + NVALID + (t0 - b * NPADROW)] = ws[WS_LPAD];
        }
        const float4 pp = *(const float4*)&ws[WS_PPAD + ((tid & 31) << 2)];
        float4* out4 = (float4*)(out + LOGITS_SZ);
        const long long totalU = (long long)2 * NPADROW * 32;   // 2056384
        for (long long u = t0; u < totalU; u += 131072) {
            int rb = (int)(u >> 5);
            int b = rb / NPADROW;
            int kk = rb - b * NPADROW;
            out4[((size_t)b * TOTAL + NVALID + kk) * 32 + (int)(u & 31)] = pp;
        }
    }
}

// ---- span epilogue: 383 blocks x 4 spans ----
__global__ __launch_bounds__(256) void k_span(const float* __restrict__ w_p2,
                                              const float* __restrict__ b_p1,
                                              const float* __restrict__ b_p2,
                                              const float* __restrict__ ws,
                                              float* __restrict__ out) {
    __shared__ __align__(16) float tld[D * 4];      // [d][span] 12.3 KB
    __shared__ __align__(16) float red[PD * 4];
    const int tid = threadIdx.x;
    int rs[4], re[4], rw[4], kk[4], bb[4], valid[4];
    #pragma unroll
    for (int s = 0; s < 4; ++s) {
        int q = blockIdx.x * 4 + s;
        valid[s] = q < 1530;
        int qc = valid[s] ? q : 0;
        int b = qc >= 765 ? 1 : 0;
        int k = qc - b * 765;
        int i, w; span_iw(k, i, w);
        bb[s] = b; kk[s] = k;
        rs[s] = b * S + i;
        re[s] = 512 + b * S + i + w;
        rw[s] = w;
    }
    if (tid < 4 && valid[tid])
        out[bb[tid] * TOTAL + kk[tid]] =
            ws[WS_L + rs[tid]] + ws[WS_L + re[tid]] + ws[WS_LW + rw[tid]];
    {   // phase 1: t = relu(P1s + P1e + P1w + b_p1), layout tld[d*4 + s]
        const int s = tid & 3, dbase = tid >> 2;
        const float* P1 = ws + WS_P1;
        #pragma unroll
        for (int p = 0; p < 12; ++p) {
            int dd = dbase + 64 * p;
            float v = 0.f;
            if (valid[s]) {
                v = P1[(size_t)rs[s] * D + dd] + P1[(size_t)re[s] * D + dd]
                  + P1[(size_t)(1024 + rw[s]) * D + dd] + b_p1[dd];
                v = fmaxf(v, 0.f);
            }
            tld[dd * 4 + s] = v;                    // addr = tid + 256p: conflict-free
        }
    }
    __syncthreads();
    // phase 2: proj[s][j] = sum_d t[s][d] * w_p2[d][j]
    const int j = tid & 127, h = tid >> 7;
    float a0 = 0.f, a1 = 0.f, a2 = 0.f, a3 = 0.f;
    const float* wp = w_p2 + (size_t)(h * 384) * PD + j;
    const float4* tp = (const float4*)&tld[h * 384 * 4];
    #pragma unroll 4
    for (int it = 0; it < 384; ++it) {
        float wv = wp[(size_t)it * PD];
        float4 t4 = tp[it];                          // broadcast b128
        a0 = fmaf(wv, t4.x, a0);
        a1 = fmaf(wv, t4.y, a1);
        a2 = fmaf(wv, t4.z, a2);
        a3 = fmaf(wv, t4.w, a3);
    }
    if (h) ((float4*)red)[j] = make_float4(a0, a1, a2, a3);
    __syncthreads();
    if (!h) {
        float4 o = ((float4*)red)[j];
        float vals[4] = {a0 + o.x, a1 + o.y, a2 + o.z, a3 + o.w};
        const float bp = b_p2[j];
        #pragma unroll
        for (int s = 0; s < 4; ++s)
            if (valid[s])
                out[LOGITS_SZ + ((size_t)bb[s] * TOTAL + kk[s]) * PD + j] = vals[s] + bp;
    }
}

extern "C" void kernel_launch(void* const* d_in, const int* in_sizes, int n_in,
                              void* d_out, int out_size, void* d_ws, size_t ws_size,
                              hipStream_t stream) {
    const float* hidden    = (const float*)d_in[0];
    const float* width_emb = (const float*)d_in[1];
    const float* w_span    = (const float*)d_in[2];
    const float* b_span    = (const float*)d_in[3];
    const float* w_cls     = (const float*)d_in[4];
    const float* b_cls     = (const float*)d_in[5];
    const float* w_p1      = (const float*)d_in[6];
    const float* b_p1      = (const float*)d_in[7];
    const float* w_p2      = (const float*)d_in[8];
    const float* b_p2      = (const float*)d_in[9];
    float* out = (float*)d_out;
    float* ws  = (float*)d_ws;

    hipMemsetAsync(d_ws, 0, WS_ZERO_BYTES, stream);            // zero H + P1 accum
    k_prepA<<<49, 256, 0, stream>>>(width_emb, w_span, b_span, w_cls, b_cls, w_p1, b_p1, ws);
    k_gemm1<<<dim3(8, 24, 2), 256, 0, stream>>>(hidden, w_span, ws);
    k_prepB<<<258, 256, 0, stream>>>(w_cls, b_cls, w_p2, b_p2, ws);
    k_gemm2_fill<<<920, 256, 0, stream>>>(w_p1, ws, out);
    k_span<<<383, 256, 0, stream>>>(w_p2, b_p1, b_p2, ws, out);
}

// Round 4
// 236.924 us; speedup vs baseline: 1.1182x; 1.0407x over previous
//
#include <hip/hip_runtime.h>

// SpanNER fp32, occupancy-optimized, no atomics:
//  K1: Hp[z] partials of hidden@[A_s|A_e] (768 blks) + WE3 rows + TPAD/PPAD/LPAD
//  K2: Pp[z] partials of Hsum@w_p1 (816 blks) + L[1024] + LW[3]
//  K3: pad fill (512 blks) + span epilogue (383 blks x 4 spans)

#define D 768
#define S 256
#define TOTAL 32896
#define NVALID 765
#define NPADROW (TOTAL - NVALID)   // 32131
#define PD 128
#define LOGITS_SZ (2 * TOTAL)      // 65792
#define MROWS 1088                 // 34 * 32 (covers 1027 real rows)

// workspace offsets (floats)
#define WS_HP   0                          // [2][1088][768]
#define WS_PP   (2 * MROWS * D)            // [2][1088][768]
#define WS_L    (4 * MROWS * D)            // [1024]
#define WS_LW   (WS_L + 1024)              // [3]
#define WS_LPAD (WS_LW + 3)                // [1]
#define WS_PPAD (WS_LPAD + 4)              // [128], 16B aligned

__device__ __forceinline__ void span_iw(int k, int& i, int& w) {
    if (k < 762)      { i = k / 3;  w = k - i * 3; }
    else if (k < 764) { i = 254;    w = k - 762; }
    else              { i = 255;    w = 0; }
}

// ================= K1 =================
__global__ __launch_bounds__(256) void k_stage1(const float* __restrict__ hidden,
                                                const float* __restrict__ width_emb,
                                                const float* __restrict__ w_span,
                                                const float* __restrict__ b_span,
                                                const float* __restrict__ w_cls,
                                                const float* __restrict__ b_cls,
                                                const float* __restrict__ w_p1,
                                                const float* __restrict__ b_p1,
                                                const float* __restrict__ w_p2,
                                                const float* __restrict__ b_p2,
                                                float* __restrict__ ws) {
    const int bid = blockIdx.x, tid = threadIdx.x;
    if (bid < 768) {
        // GEMM1: 32x64 tile, K-split 2. Hp[z][g*512+r][n] = hidden @ A_g (partial)
        const int z = bid & 1, t = bid >> 1;
        const int mt = t & 15, nt = t >> 4;            // mt 0..15, nt 0..23
        const int m0 = mt * 32, k0 = z * 384;
        const int g = nt >= 12;
        const int n0 = (nt - (g ? 12 : 0)) * 64;
        const float* B = w_span + ((size_t)g * D + k0) * D;
        __shared__ float As[16][33];
        __shared__ __align__(16) float Bs[16][64];
        const int arow = tid >> 3, ak2 = (tid & 7) << 1;
        const int bkr = tid >> 4, bjq = (tid & 15) << 2;
        const int crow = (tid >> 4) << 1, ccq = (tid & 15) << 2;
        float acc[2][4] = {};
        float2 av = *(const float2*)&hidden[(size_t)(m0 + arow) * D + k0 + ak2];
        float4 bv = *(const float4*)&B[(size_t)bkr * D + n0 + bjq];
        for (int kt = 0; kt < 24; ++kt) {
            As[ak2][arow] = av.x; As[ak2 + 1][arow] = av.y;
            *(float4*)&Bs[bkr][bjq] = bv;
            __syncthreads();
            if (kt + 1 < 24) {
                av = *(const float2*)&hidden[(size_t)(m0 + arow) * D + k0 + (kt + 1) * 16 + ak2];
                bv = *(const float4*)&B[(size_t)((kt + 1) * 16 + bkr) * D + n0 + bjq];
            }
            #pragma unroll
            for (int k = 0; k < 16; ++k) {
                float a0 = As[k][crow], a1 = As[k][crow + 1];
                float4 b4 = *(const float4*)&Bs[k][ccq];
                acc[0][0] = fmaf(a0, b4.x, acc[0][0]);
                acc[0][1] = fmaf(a0, b4.y, acc[0][1]);
                acc[0][2] = fmaf(a0, b4.z, acc[0][2]);
                acc[0][3] = fmaf(a0, b4.w, acc[0][3]);
                acc[1][0] = fmaf(a1, b4.x, acc[1][0]);
                acc[1][1] = fmaf(a1, b4.y, acc[1][1]);
                acc[1][2] = fmaf(a1, b4.z, acc[1][2]);
                acc[1][3] = fmaf(a1, b4.w, acc[1][3]);
            }
            __syncthreads();
        }
        float* Hp = ws + WS_HP;
        size_t rbase = ((size_t)z * MROWS + g * 512 + m0 + crow) * D + n0 + ccq;
        *(float4*)&Hp[rbase]     = make_float4(acc[0][0], acc[0][1], acc[0][2], acc[0][3]);
        *(float4*)&Hp[rbase + D] = make_float4(acc[1][0], acc[1][1], acc[1][2], acc[1][3]);
    } else if (bid == 768) {
        // WE3[w] = width_emb[w]@A_w + b_span -> Hp[0][1024+w]; zeros -> Hp[1][1024+w]
        const float* Aw = w_span + (size_t)(2 * D) * D;
        float acc[3][3] = {};
        for (int k = 0; k < D; ++k) {
            float e0 = width_emb[k], e1 = width_emb[D + k], e2 = width_emb[2 * D + k];
            const float* r = Aw + (size_t)k * D + tid;
            #pragma unroll
            for (int p = 0; p < 3; ++p) {
                float a = r[p * 256];
                acc[0][p] = fmaf(e0, a, acc[0][p]);
                acc[1][p] = fmaf(e1, a, acc[1][p]);
                acc[2][p] = fmaf(e2, a, acc[2][p]);
            }
        }
        float* Hp = ws + WS_HP;
        #pragma unroll
        for (int w = 0; w < 3; ++w)
            #pragma unroll
            for (int p = 0; p < 3; ++p) {
                int col = tid + p * 256;
                Hp[(size_t)(1024 + w) * D + col] = acc[w][p] + b_span[col];
                Hp[((size_t)MROWS + 1024 + w) * D + col] = 0.f;
            }
    } else {
        // TPAD (LDS) -> PPAD -> LPAD
        __shared__ float tp[D];
        __shared__ float red[PD];
        float a0 = b_p1[tid], a1 = b_p1[tid + 256], a2 = b_p1[tid + 512];
        for (int k = 0; k < D; ++k) {
            float bs = b_span[k];
            const float* r = w_p1 + (size_t)k * D + tid;
            a0 = fmaf(bs, r[0],   a0);
            a1 = fmaf(bs, r[256], a1);
            a2 = fmaf(bs, r[512], a2);
        }
        tp[tid] = fmaxf(a0, 0.f); tp[tid + 256] = fmaxf(a1, 0.f); tp[tid + 512] = fmaxf(a2, 0.f);
        __syncthreads();
        const int j = tid & 127, h = tid >> 7;
        float acc = 0.f;
        #pragma unroll 4
        for (int it = 0; it < 384; ++it) {
            int d = h * 384 + it;
            acc = fmaf(tp[d], w_p2[(size_t)d * PD + j], acc);
        }
        if (h) red[j] = acc;
        __syncthreads();
        if (!h) ws[WS_PPAD + j] = acc + red[j] + b_p2[j];
        if (tid < 64) {
            float a = 0.f;
            for (int i = 0; i < 12; ++i) a = fmaf(b_span[tid + 64 * i], w_cls[tid + 64 * i], a);
            for (int off = 32; off > 0; off >>= 1) a += __shfl_down(a, off, 64);
            if (tid == 0) ws[WS_LPAD] = a + b_cls[0];
        }
    }
}

// ================= K2 =================
__global__ __launch_bounds__(256) void k_stage2(const float* __restrict__ w_p1,
                                                const float* __restrict__ w_cls,
                                                const float* __restrict__ b_cls,
                                                float* __restrict__ ws) {
    const int bid = blockIdx.x, tid = threadIdx.x;
    const float* Hp0 = ws + WS_HP;
    const float* Hp1 = Hp0 + (size_t)MROWS * D;
    if (bid < 816) {
        // GEMM2: Pp[z][row][n] = (Hp0+Hp1) @ w_p1 (partial over K-half z)
        const int z = bid & 1, t = bid >> 1;            // t 0..407
        const int mt = t % 34, nt = t / 34;             // mt 0..33, nt 0..11
        const int m0 = mt * 32, n0 = nt * 64, k0 = z * 384;
        __shared__ float As[16][33];
        __shared__ __align__(16) float Bs[16][64];
        const int arow = tid >> 3, ak2 = (tid & 7) << 1;
        const int bkr = tid >> 4, bjq = (tid & 15) << 2;
        const int crow = (tid >> 4) << 1, ccq = (tid & 15) << 2;
        const size_t aoff = (size_t)(m0 + arow) * D + k0 + ak2;
        float acc[2][4] = {};
        float2 av0 = *(const float2*)&Hp0[aoff];
        float2 av1 = *(const float2*)&Hp1[aoff];
        float4 bv = *(const float4*)&w_p1[(size_t)(k0 + bkr) * D + n0 + bjq];
        for (int kt = 0; kt < 24; ++kt) {
            As[ak2][arow]     = av0.x + av1.x;
            As[ak2 + 1][arow] = av0.y + av1.y;
            *(float4*)&Bs[bkr][bjq] = bv;
            __syncthreads();
            if (kt + 1 < 24) {
                av0 = *(const float2*)&Hp0[aoff + (kt + 1) * 16];
                av1 = *(const float2*)&Hp1[aoff + (kt + 1) * 16];
                bv  = *(const float4*)&w_p1[(size_t)(k0 + (kt + 1) * 16 + bkr) * D + n0 + bjq];
            }
            #pragma unroll
            for (int k = 0; k < 16; ++k) {
                float a0 = As[k][crow], a1 = As[k][crow + 1];
                float4 b4 = *(const float4*)&Bs[k][ccq];
                acc[0][0] = fmaf(a0, b4.x, acc[0][0]);
                acc[0][1] = fmaf(a0, b4.y, acc[0][1]);
                acc[0][2] = fmaf(a0, b4.z, acc[0][2]);
                acc[0][3] = fmaf(a0, b4.w, acc[0][3]);
                acc[1][0] = fmaf(a1, b4.x, acc[1][0]);
                acc[1][1] = fmaf(a1, b4.y, acc[1][1]);
                acc[1][2] = fmaf(a1, b4.z, acc[1][2]);
                acc[1][3] = fmaf(a1, b4.w, acc[1][3]);
            }
            __syncthreads();
        }
        float* Pp = ws + WS_PP + (size_t)z * MROWS * D;
        #pragma unroll
        for (int e = 0; e < 2; ++e) {
            int row = m0 + crow + e;
            if (row < 1027)
                *(float4*)&Pp[(size_t)row * D + n0 + ccq] =
                    make_float4(acc[e][0], acc[e][1], acc[e][2], acc[e][3]);
        }
    } else if (bid < 848) {
        // L[r] = (Hp0[r]+Hp1[r]) . w_cls      (1024 rows)
        const int w = tid >> 6, lane = tid & 63;
        const int rbase = (bid - 816) * 32 + w * 8;
        for (int rr = 0; rr < 8; ++rr) {
            const int r = rbase + rr;
            const float* h0 = Hp0 + (size_t)r * D;
            const float* h1 = Hp1 + (size_t)r * D;
            float a = 0.f;
            #pragma unroll
            for (int i = 0; i < 12; ++i) {
                int d = lane + 64 * i;
                a = fmaf(h0[d] + h1[d], w_cls[d], a);
            }
            for (int off = 32; off > 0; off >>= 1) a += __shfl_down(a, off, 64);
            if (lane == 0) ws[WS_L + r] = a;
        }
    } else {
        // LW[w] = WE3[w] . w_cls + b_cls
        if (tid < 192) {
            const int w = tid >> 6, lane = tid & 63;
            const float* h0 = Hp0 + (size_t)(1024 + w) * D;
            float a = 0.f;
            #pragma unroll
            for (int i = 0; i < 12; ++i) {
                int d = lane + 64 * i;
                a = fmaf(h0[d], w_cls[d], a);
            }
            for (int off = 32; off > 0; off >>= 1) a += __shfl_down(a, off, 64);
            if (lane == 0) ws[WS_LW + w] = a + b_cls[0];
        }
    }
}

// ================= K3 =================
__global__ __launch_bounds__(256) void k_stage3(const float* __restrict__ w_p2,
                                                const float* __restrict__ b_p1,
                                                const float* __restrict__ b_p2,
                                                const float* __restrict__ ws,
                                                float* __restrict__ out) {
    const int bid = blockIdx.x, tid = threadIdx.x;
    if (bid < 512) {
        // constant pad fill: logits + 33 MB proj rows
        const int t0 = bid * 256 + tid;                     // 0..131071
        if (t0 < 2 * NPADROW) {
            int b = t0 / NPADROW;
            out[b * TOTAL + NVALID + (t0 - b * NPADROW)] = ws[WS_LPAD];
        }
        const float4 pp = *(const float4*)&ws[WS_PPAD + ((tid & 31) << 2)];
        float4* out4 = (float4*)(out + LOGITS_SZ);
        const long long totalU = (long long)2 * NPADROW * 32;   // 2056384
        for (long long u = t0; u < totalU; u += 131072) {
            int rb = (int)(u >> 5);
            int b = rb / NPADROW;
            int kk = rb - b * NPADROW;
            out4[((size_t)b * TOTAL + NVALID + kk) * 32 + (int)(u & 31)] = pp;
        }
        return;
    }
    // span epilogue: 4 spans per block
    const int sb = bid - 512;                               // 0..382
    __shared__ float tld[D * 5];                            // stride 5: conflict-free
    __shared__ float red[4 * PD];
    const float* P0 = ws + WS_PP;
    const float* P1z = P0 + (size_t)MROWS * D;
    {   // phase 1: t = relu(sum of 2 partials x 3 rows + b_p1)
        const int s = tid >> 6, dl = tid & 63;
        const int q = sb * 4 + s;
        const int v = q < 1530;
        const int qc = v ? q : 0;
        const int b = qc >= 765;
        const int k = qc - 765 * b;
        int i, w; span_iw(k, i, w);
        const size_t rs = (size_t)(b * S + i) * D;
        const size_t re = (size_t)(512 + b * S + i + w) * D;
        const size_t rw = (size_t)(1024 + w) * D;
        #pragma unroll
        for (int p = 0; p < 12; ++p) {
            int dd = dl + 64 * p;
            float val = P0[rs + dd] + P1z[rs + dd] + P0[re + dd] + P1z[re + dd]
                      + P0[rw + dd] + P1z[rw + dd] + b_p1[dd];
            tld[dd * 5 + s] = v ? fmaxf(val, 0.f) : 0.f;
        }
    }
    if (tid < 4) {                                          // logits
        int q2 = sb * 4 + tid;
        if (q2 < 1530) {
            int b2 = q2 >= 765, k2 = q2 - 765 * b2, i2, w2;
            span_iw(k2, i2, w2);
            out[b2 * TOTAL + k2] = ws[WS_L + b2 * S + i2]
                                 + ws[WS_L + 512 + b2 * S + i2 + w2] + ws[WS_LW + w2];
        }
    }
    __syncthreads();
    // phase 2: proj[s][j] = sum_d t[s][d] * w_p2[d][j]
    const int j = tid & 127, h = tid >> 7;
    float a[4] = {0.f, 0.f, 0.f, 0.f};
    const float* wp = w_p2 + (size_t)h * 384 * PD + j;
    const float* tb = tld + h * 384 * 5;
    #pragma unroll 4
    for (int it = 0; it < 384; ++it) {
        float wv = wp[(size_t)it * PD];
        #pragma unroll
        for (int s4 = 0; s4 < 4; ++s4)
            a[s4] = fmaf(wv, tb[it * 5 + s4], a[s4]);
    }
    if (h) {
        #pragma unroll
        for (int s4 = 0; s4 < 4; ++s4) red[s4 * PD + j] = a[s4];
    }
    __syncthreads();
    if (!h) {
        const float bp = b_p2[j];
        #pragma unroll
        for (int s4 = 0; s4 < 4; ++s4) {
            int q2 = sb * 4 + s4;
            if (q2 < 1530) {
                int b2 = q2 >= 765, k2 = q2 - 765 * b2;
                out[LOGITS_SZ + ((size_t)b2 * TOTAL + k2) * PD + j] =
                    a[s4] + red[s4 * PD + j] + bp;
            }
        }
    }
}

extern "C" void kernel_launch(void* const* d_in, const int* in_sizes, int n_in,
                              void* d_out, int out_size, void* d_ws, size_t ws_size,
                              hipStream_t stream) {
    const float* hidden    = (const float*)d_in[0];
    const float* width_emb = (const float*)d_in[1];
    const float* w_span    = (const float*)d_in[2];
    const float* b_span    = (const float*)d_in[3];
    const float* w_cls     = (const float*)d_in[4];
    const float* b_cls     = (const float*)d_in[5];
    const float* w_p1      = (const float*)d_in[6];
    const float* b_p1      = (const float*)d_in[7];
    const float* w_p2      = (const float*)d_in[8];
    const float* b_p2      = (const float*)d_in[9];
    float* out = (float*)d_out;
    float* ws  = (float*)d_ws;   // ~13.4 MB used

    k_stage1<<<770, 256, 0, stream>>>(hidden, width_emb, w_span, b_span, w_cls, b_cls,
                                      w_p1, b_p1, w_p2, b_p2, ws);
    k_stage2<<<849, 256, 0, stream>>>(w_p1, w_cls, b_cls, ws);
    k_stage3<<<895, 256, 0, stream>>>(w_p2, b_p1, b_p2, ws, out);
}

// Round 5
// 182.729 us; speedup vs baseline: 1.4499x; 1.2966x over previous
//
#include <hip/hip_runtime.h>

// SpanNER via split-bf16 MFMA (3-term: AhBh + AhBl + AlBh, ~2^-17 rel error):
//  k_prep  : hidden->bf16 h/l; w_span(A_s,A_e)->transposed bf16 h/l; w_p1->transposed h/l;
//            WE3 rows (bf16 h/l into H rows 1024..1026); TPAD; LPAD
//  k_mg1   : H(bf16 h/l, rows 0..1023) = hidden @ [A_s|A_e] via MFMA; +PPAD block
//  k_mg2   : P1(fp32) = Hext @ w_p1 via MFMA; +L dots(1024); +LW
//  k_stage3: pad fill (512 blks) + span epilogue (383 blks x 4 spans)

typedef unsigned short u16;
typedef __attribute__((ext_vector_type(8))) short bf16x8;
typedef __attribute__((ext_vector_type(8))) unsigned short u16x8;
typedef __attribute__((ext_vector_type(4))) float f32x4;

#define D 768
#define S 256
#define TOTAL 32896
#define NVALID 765
#define NPADROW (TOTAL - NVALID)   // 32131
#define PD 128
#define LOGITS_SZ (2 * TOTAL)      // 65792
#define MROWS 1088                 // 17*64 (covers 1027 real rows)

// float ws region
#define WS_P1   0                  // [1088][768] fp32
#define WS_TPAD 835584             // [768]
#define WS_L    836352             // [1024]
#define WS_LW   837376             // [3]
#define WS_LPAD 837379             // [1]
#define WS_PPAD 837380             // [128] (16B aligned)
#define US_BYTE_OFF (837632 * 4)
// ushort (bf16) offsets within region starting at US_BYTE_OFF
#define US_HH  0                   // [1088][768] H hi
#define US_HL  835584              // H lo
#define US_AH  1671168             // [512][768] hidden hi
#define US_AL  2064384             // hidden lo
#define US_B1H 2457600             // [1536][768] [A_s|A_e]^T hi
#define US_B1L 3637248             // lo
#define US_W1H 4816896             // [768][768] w_p1^T hi
#define US_W1L 5406720             // lo
// total ws ~15.4 MB

__device__ __forceinline__ u16 f2bf(float v) {
    unsigned u = __float_as_uint(v);
    u += 0x7fffu + ((u >> 16) & 1u);
    return (u16)(u >> 16);
}
__device__ __forceinline__ float bf2f(u16 h) {
    return __uint_as_float(((unsigned)h) << 16);
}

__device__ __forceinline__ void span_iw(int k, int& i, int& w) {
    if (k < 762)      { i = k / 3;  w = k - i * 3; }
    else if (k < 764) { i = 254;    w = k - 762; }
    else              { i = 255;    w = 0; }
}

// ==================== k_prep (673 blocks) ====================
__global__ __launch_bounds__(256) void k_prep(const float* __restrict__ hidden,
                                              const float* __restrict__ width_emb,
                                              const float* __restrict__ w_span,
                                              const float* __restrict__ b_span,
                                              const float* __restrict__ w_cls,
                                              const float* __restrict__ b_cls,
                                              const float* __restrict__ w_p1,
                                              const float* __restrict__ b_p1,
                                              float* __restrict__ ws) {
    u16* us = (u16*)((char*)ws + US_BYTE_OFF);
    const int bid = blockIdx.x, tid = threadIdx.x;
    __shared__ u16 Th[64][72];
    __shared__ u16 Tl[64][72];
    __shared__ float red[256];

    if (bid < 192) {                       // hidden -> Ah/Al bf16
        const int e0 = bid * 2048 + tid * 8;
        float4 v0 = *(const float4*)&hidden[e0];
        float4 v1 = *(const float4*)&hidden[e0 + 4];
        float f[8] = {v0.x, v0.y, v0.z, v0.w, v1.x, v1.y, v1.z, v1.w};
        u16x8 h, l;
        #pragma unroll
        for (int c = 0; c < 8; ++c) {
            u16 hh = f2bf(f[c]);
            h[c] = hh;
            l[c] = f2bf(f[c] - bf2f(hh));
        }
        *(u16x8*)&us[US_AH + e0] = h;
        *(u16x8*)&us[US_AL + e0] = l;
        return;
    }
    const float* tsrc = nullptr;
    u16 *tdh = nullptr, *tdl = nullptr;
    int kb = 0, nb = 0;
    if (bid < 480) {                       // w_span A_s/A_e transpose tiles
        int t2 = bid - 192;
        int g = t2 / 144, rem = t2 % 144;
        kb = rem / 12; nb = rem % 12;
        tsrc = w_span + (size_t)g * D * D;
        tdh = us + US_B1H + (size_t)g * D * D;
        tdl = us + US_B1L + (size_t)g * D * D;
    } else if (bid < 624) {                // w_p1 transpose tiles
        int t3 = bid - 480;
        kb = t3 / 12; nb = t3 % 12;
        tsrc = w_p1;
        tdh = us + US_W1H;
        tdl = us + US_W1L;
    }
    if (tsrc) {
        // phase1: read 64x64 fp32 tile coalesced, store transposed h/l to LDS
        #pragma unroll
        for (int r4 = 0; r4 < 4; ++r4) {
            const int srow = r4 * 16 + (tid >> 4);
            const int scol = (tid & 15) * 4;
            float4 v = *(const float4*)&tsrc[(size_t)(kb * 64 + srow) * D + nb * 64 + scol];
            float f[4] = {v.x, v.y, v.z, v.w};
            #pragma unroll
            for (int c = 0; c < 4; ++c) {
                u16 hh = f2bf(f[c]);
                Th[scol + c][srow] = hh;
                Tl[scol + c][srow] = f2bf(f[c] - bf2f(hh));
            }
        }
        __syncthreads();
        // phase2: write rows of B^T (k-contiguous) coalesced
        const int orow = tid >> 2, kp = (tid & 3) * 16;
        const size_t didx = (size_t)(nb * 64 + orow) * D + kb * 64 + kp;
        *(u16x8*)&tdh[didx]     = *(const u16x8*)&Th[orow][kp];
        *(u16x8*)&tdh[didx + 8] = *(const u16x8*)&Th[orow][kp + 8];
        *(u16x8*)&tdl[didx]     = *(const u16x8*)&Tl[orow][kp];
        *(u16x8*)&tdl[didx + 8] = *(const u16x8*)&Tl[orow][kp + 8];
        return;
    }
    const int dl = tid & 63, kc = tid >> 6;
    if (bid < 660) {                       // WE3[w] -> H rows 1024..1026 (h/l)
        const int t4 = bid - 624;
        const int w = t4 / 12, seg = t4 % 12;
        const int d = seg * 64 + dl;
        const float* Aw = w_span + (size_t)(2 * D) * D;
        const float* we = width_emb + w * D;
        float p = 0.f;
        #pragma unroll 4
        for (int k = kc * 192; k < kc * 192 + 192; ++k)
            p = fmaf(we[k], Aw[(size_t)k * D + d], p);
        red[tid] = p; __syncthreads();
        if (kc == 0) {
            float v = red[dl] + red[64 + dl] + red[128 + dl] + red[192 + dl] + b_span[d];
            u16 hh = f2bf(v);
            const size_t idx = (size_t)(1024 + w) * D + d;
            us[US_HH + idx] = hh;
            us[US_HL + idx] = f2bf(v - bf2f(hh));
        }
    } else if (bid < 672) {                // TPAD = relu(b_span@w_p1 + b_p1)
        const int d = (bid - 660) * 64 + dl;
        float p = 0.f;
        #pragma unroll 4
        for (int k = kc * 192; k < kc * 192 + 192; ++k)
            p = fmaf(b_span[k], w_p1[(size_t)k * D + d], p);
        red[tid] = p; __syncthreads();
        if (kc == 0) {
            float v = red[dl] + red[64 + dl] + red[128 + dl] + red[192 + dl] + b_p1[d];
            ws[WS_TPAD + d] = fmaxf(v, 0.f);
        }
    } else {                               // LPAD = b_span . w_cls + b_cls
        if (tid < 64) {
            float a = 0.f;
            #pragma unroll
            for (int i = 0; i < 12; ++i) a = fmaf(b_span[tid + 64 * i], w_cls[tid + 64 * i], a);
            for (int off = 32; off > 0; off >>= 1) a += __shfl_down(a, off, 64);
            if (tid == 0) ws[WS_LPAD] = a + b_cls[0];
        }
    }
}

#define MFMA(A, B, C) __builtin_amdgcn_mfma_f32_16x16x32_bf16(A, B, C, 0, 0, 0)

// ==================== k_mg1 (193 blocks): H = hidden @ [A_s|A_e] ====================
__global__ __launch_bounds__(256) void k_mg1(const float* __restrict__ w_p2,
                                             const float* __restrict__ b_p2,
                                             float* __restrict__ ws) {
    u16* us = (u16*)((char*)ws + US_BYTE_OFF);
    const int bid = blockIdx.x, tid = threadIdx.x;
    __shared__ u16 LA_h[64][40], LA_l[64][40], LB_h[64][40], LB_l[64][40];
    __shared__ float redp[128];
    if (bid < 192) {
        const int mt = bid / 24, nt = bid % 24;
        const int m0 = mt * 64, n0 = nt * 64;          // n0 in [0,1536)
        const int row = tid >> 2, kp = (tid & 3) * 8;
        const u16* Ah = us + US_AH; const u16* Al = us + US_AL;
        const u16* Bh = us + US_B1H; const u16* Bl = us + US_B1L;
        const size_t aoff = (size_t)(m0 + row) * D + kp;
        const size_t boff = (size_t)(n0 + row) * D + kp;
        u16x8 ra_h = *(const u16x8*)&Ah[aoff];
        u16x8 ra_l = *(const u16x8*)&Al[aoff];
        u16x8 rb_h = *(const u16x8*)&Bh[boff];
        u16x8 rb_l = *(const u16x8*)&Bl[boff];
        const int wv = tid >> 6, lane = tid & 63;
        const int wm = wv & 1, wn = wv >> 1;
        const int lr = lane & 15, lk = (lane >> 4) * 8;
        f32x4 acc00 = {0,0,0,0}, acc01 = {0,0,0,0}, acc10 = {0,0,0,0}, acc11 = {0,0,0,0};
        for (int kt = 0; kt < 24; ++kt) {
            *(u16x8*)&LA_h[row][kp] = ra_h;
            *(u16x8*)&LA_l[row][kp] = ra_l;
            *(u16x8*)&LB_h[row][kp] = rb_h;
            *(u16x8*)&LB_l[row][kp] = rb_l;
            __syncthreads();
            if (kt < 23) {
                ra_h = *(const u16x8*)&Ah[aoff + (kt + 1) * 32];
                ra_l = *(const u16x8*)&Al[aoff + (kt + 1) * 32];
                rb_h = *(const u16x8*)&Bh[boff + (kt + 1) * 32];
                rb_l = *(const u16x8*)&Bl[boff + (kt + 1) * 32];
            }
            bf16x8 ah0 = *(const bf16x8*)&LA_h[wm * 32 + lr][lk];
            bf16x8 ah1 = *(const bf16x8*)&LA_h[wm * 32 + 16 + lr][lk];
            bf16x8 al0 = *(const bf16x8*)&LA_l[wm * 32 + lr][lk];
            bf16x8 al1 = *(const bf16x8*)&LA_l[wm * 32 + 16 + lr][lk];
            bf16x8 bh0 = *(const bf16x8*)&LB_h[wn * 32 + lr][lk];
            bf16x8 bh1 = *(const bf16x8*)&LB_h[wn * 32 + 16 + lr][lk];
            bf16x8 bl0 = *(const bf16x8*)&LB_l[wn * 32 + lr][lk];
            bf16x8 bl1 = *(const bf16x8*)&LB_l[wn * 32 + 16 + lr][lk];
            acc00 = MFMA(ah0, bh0, acc00); acc00 = MFMA(ah0, bl0, acc00); acc00 = MFMA(al0, bh0, acc00);
            acc01 = MFMA(ah0, bh1, acc01); acc01 = MFMA(ah0, bl1, acc01); acc01 = MFMA(al0, bh1, acc01);
            acc10 = MFMA(ah1, bh0, acc10); acc10 = MFMA(ah1, bl0, acc10); acc10 = MFMA(al1, bh0, acc10);
            acc11 = MFMA(ah1, bh1, acc11); acc11 = MFMA(ah1, bl1, acc11); acc11 = MFMA(al1, bh1, acc11);
            __syncthreads();
        }
        const int g = (n0 >= D);
        u16* Hh = us + US_HH; u16* Hl = us + US_HL;
        #define WR1(ACC, FM, FN) { \
            const int rr0 = g * 512 + m0 + wm * 32 + FM * 16 + (lane >> 4) * 4; \
            const int cc = n0 - g * D + wn * 32 + FN * 16 + lr; \
            _Pragma("unroll") \
            for (int r = 0; r < 4; ++r) { \
                float v = ACC[r]; \
                u16 hh = f2bf(v); \
                const size_t idx = (size_t)(rr0 + r) * D + cc; \
                Hh[idx] = hh; Hl[idx] = f2bf(v - bf2f(hh)); \
            } }
        WR1(acc00, 0, 0) WR1(acc01, 0, 1) WR1(acc10, 1, 0) WR1(acc11, 1, 1)
        #undef WR1
    } else {
        // PPAD = TPAD @ w_p2 + b_p2
        const int j = tid & 127, h2 = tid >> 7;
        float acc = 0.f;
        #pragma unroll 4
        for (int it = 0; it < 384; ++it) {
            const int d = h2 * 384 + it;
            acc = fmaf(ws[WS_TPAD + d], w_p2[(size_t)d * PD + j], acc);
        }
        if (h2) redp[j] = acc;
        __syncthreads();
        if (!h2) ws[WS_PPAD + j] = acc + redp[j] + b_p2[j];
    }
}

// ==================== k_mg2 (237 blocks): P1 = Hext @ w_p1; L; LW ====================
__global__ __launch_bounds__(256) void k_mg2(const float* __restrict__ w_cls,
                                             const float* __restrict__ b_cls,
                                             float* __restrict__ ws) {
    u16* us = (u16*)((char*)ws + US_BYTE_OFF);
    const int bid = blockIdx.x, tid = threadIdx.x;
    __shared__ u16 LA_h[64][40], LA_l[64][40], LB_h[64][40], LB_l[64][40];
    if (bid < 204) {
        const int mt = bid / 12, nt = bid % 12;        // mt 0..16
        const int m0 = mt * 64, n0 = nt * 64;
        const int row = tid >> 2, kp = (tid & 3) * 8;
        const u16* Ah = us + US_HH; const u16* Al = us + US_HL;
        const u16* Bh = us + US_W1H; const u16* Bl = us + US_W1L;
        const size_t aoff = (size_t)(m0 + row) * D + kp;
        const size_t boff = (size_t)(n0 + row) * D + kp;
        u16x8 ra_h = *(const u16x8*)&Ah[aoff];
        u16x8 ra_l = *(const u16x8*)&Al[aoff];
        u16x8 rb_h = *(const u16x8*)&Bh[boff];
        u16x8 rb_l = *(const u16x8*)&Bl[boff];
        const int wv = tid >> 6, lane = tid & 63;
        const int wm = wv & 1, wn = wv >> 1;
        const int lr = lane & 15, lk = (lane >> 4) * 8;
        f32x4 acc00 = {0,0,0,0}, acc01 = {0,0,0,0}, acc10 = {0,0,0,0}, acc11 = {0,0,0,0};
        for (int kt = 0; kt < 24; ++kt) {
            *(u16x8*)&LA_h[row][kp] = ra_h;
            *(u16x8*)&LA_l[row][kp] = ra_l;
            *(u16x8*)&LB_h[row][kp] = rb_h;
            *(u16x8*)&LB_l[row][kp] = rb_l;
            __syncthreads();
            if (kt < 23) {
                ra_h = *(const u16x8*)&Ah[aoff + (kt + 1) * 32];
                ra_l = *(const u16x8*)&Al[aoff + (kt + 1) * 32];
                rb_h = *(const u16x8*)&Bh[boff + (kt + 1) * 32];
                rb_l = *(const u16x8*)&Bl[boff + (kt + 1) * 32];
            }
            bf16x8 ah0 = *(const bf16x8*)&LA_h[wm * 32 + lr][lk];
            bf16x8 ah1 = *(const bf16x8*)&LA_h[wm * 32 + 16 + lr][lk];
            bf16x8 al0 = *(const bf16x8*)&LA_l[wm * 32 + lr][lk];
            bf16x8 al1 = *(const bf16x8*)&LA_l[wm * 32 + 16 + lr][lk];
            bf16x8 bh0 = *(const bf16x8*)&LB_h[wn * 32 + lr][lk];
            bf16x8 bh1 = *(const bf16x8*)&LB_h[wn * 32 + 16 + lr][lk];
            bf16x8 bl0 = *(const bf16x8*)&LB_l[wn * 32 + lr][lk];
            bf16x8 bl1 = *(const bf16x8*)&LB_l[wn * 32 + 16 + lr][lk];
            acc00 = MFMA(ah0, bh0, acc00); acc00 = MFMA(ah0, bl0, acc00); acc00 = MFMA(al0, bh0, acc00);
            acc01 = MFMA(ah0, bh1, acc01); acc01 = MFMA(ah0, bl1, acc01); acc01 = MFMA(al0, bh1, acc01);
            acc10 = MFMA(ah1, bh0, acc10); acc10 = MFMA(ah1, bl0, acc10); acc10 = MFMA(al1, bh0, acc10);
            acc11 = MFMA(ah1, bh1, acc11); acc11 = MFMA(ah1, bl1, acc11); acc11 = MFMA(al1, bh1, acc11);
            __syncthreads();
        }
        float* P1 = ws + WS_P1;
        #define WR2(ACC, FM, FN) { \
            const int rr0 = m0 + wm * 32 + FM * 16 + (lane >> 4) * 4; \
            const int cc = n0 + wn * 32 + FN * 16 + lr; \
            _Pragma("unroll") \
            for (int r = 0; r < 4; ++r) \
                P1[(size_t)(rr0 + r) * D + cc] = ACC[r]; \
            }
        WR2(acc00, 0, 0) WR2(acc01, 0, 1) WR2(acc10, 1, 0) WR2(acc11, 1, 1)
        #undef WR2
    } else if (bid < 236) {
        // L[r] = (Hh[r]+Hl[r]) . w_cls
        const int w64 = tid >> 6, lane = tid & 63;
        const int rbase = (bid - 204) * 32 + w64 * 8;
        for (int rr = 0; rr < 8; ++rr) {
            const int r = rbase + rr;
            const u16* hh = us + US_HH + (size_t)r * D;
            const u16* hl = us + US_HL + (size_t)r * D;
            float a = 0.f;
            #pragma unroll
            for (int i = 0; i < 12; ++i) {
                const int d = lane + 64 * i;
                a = fmaf(bf2f(hh[d]) + bf2f(hl[d]), w_cls[d], a);
            }
            for (int off = 32; off > 0; off >>= 1) a += __shfl_down(a, off, 64);
            if (lane == 0) ws[WS_L + r] = a;
        }
    } else {
        // LW[w] = WE3[w] . w_cls + b_cls
        if (tid < 192) {
            const int w = tid >> 6, lane = tid & 63;
            const u16* hh = us + US_HH + (size_t)(1024 + w) * D;
            const u16* hl = us + US_HL + (size_t)(1024 + w) * D;
            float a = 0.f;
            #pragma unroll
            for (int i = 0; i < 12; ++i) {
                const int d = lane + 64 * i;
                a = fmaf(bf2f(hh[d]) + bf2f(hl[d]), w_cls[d], a);
            }
            for (int off = 32; off > 0; off >>= 1) a += __shfl_down(a, off, 64);
            if (lane == 0) ws[WS_LW + w] = a + b_cls[0];
        }
    }
}

// ==================== k_stage3 (895 blocks) ====================
__global__ __launch_bounds__(256) void k_stage3(const float* __restrict__ w_p2,
                                                const float* __restrict__ b_p1,
                                                const float* __restrict__ b_p2,
                                                const float* __restrict__ ws,
                                                float* __restrict__ out) {
    const int bid = blockIdx.x, tid = threadIdx.x;
    if (bid < 512) {
        // constant pad fill: logits + 33 MB proj rows
        const int t0 = bid * 256 + tid;
        if (t0 < 2 * NPADROW) {
            int b = t0 / NPADROW;
            out[b * TOTAL + NVALID + (t0 - b * NPADROW)] = ws[WS_LPAD];
        }
        const float4 pp = *(const float4*)&ws[WS_PPAD + ((tid & 31) << 2)];
        float4* out4 = (float4*)(out + LOGITS_SZ);
        const long long totalU = (long long)2 * NPADROW * 32;   // 2056384
        for (long long u = t0; u < totalU; u += 131072) {
            int rb = (int)(u >> 5);
            int b = rb / NPADROW;
            int kk = rb - b * NPADROW;
            out4[((size_t)b * TOTAL + NVALID + kk) * 32 + (int)(u & 31)] = pp;
        }
        return;
    }
    const int sb = bid - 512;                               // 0..382
    __shared__ float tld[D * 5];
    __shared__ float red[4 * PD];
    const float* P1 = ws + WS_P1;
    {   // phase 1: t = relu(P1s + P1e + P1w + b_p1), layout tld[d*5 + s]
        const int s = tid >> 6, dl = tid & 63;
        const int q = sb * 4 + s;
        const int v = q < 1530;
        const int qc = v ? q : 0;
        const int b = qc >= 765;
        const int k = qc - 765 * b;
        int i, w; span_iw(k, i, w);
        const size_t rs = (size_t)(b * S + i) * D;
        const size_t re = (size_t)(512 + b * S + i + w) * D;
        const size_t rw = (size_t)(1024 + w) * D;
        #pragma unroll
        for (int p = 0; p < 12; ++p) {
            const int dd = dl + 64 * p;
            float val = P1[rs + dd] + P1[re + dd] + P1[rw + dd] + b_p1[dd];
            tld[dd * 5 + s] = v ? fmaxf(val, 0.f) : 0.f;
        }
    }
    if (tid < 4) {                                          // logits
        int q2 = sb * 4 + tid;
        if (q2 < 1530) {
            int b2 = q2 >= 765, k2 = q2 - 765 * b2, i2, w2;
            span_iw(k2, i2, w2);
            out[b2 * TOTAL + k2] = ws[WS_L + b2 * S + i2]
                                 + ws[WS_L + 512 + b2 * S + i2 + w2] + ws[WS_LW + w2];
        }
    }
    __syncthreads();
    // phase 2: proj[s][j] = sum_d t[s][d] * w_p2[d][j]
    const int j = tid & 127, h = tid >> 7;
    float a[4] = {0.f, 0.f, 0.f, 0.f};
    const float* wp = w_p2 + (size_t)h * 384 * PD + j;
    const float* tb = tld + h * 384 * 5;
    #pragma unroll 4
    for (int it = 0; it < 384; ++it) {
        float wv = wp[(size_t)it * PD];
        #pragma unroll
        for (int s4 = 0; s4 < 4; ++s4)
            a[s4] = fmaf(wv, tb[it * 5 + s4], a[s4]);
    }
    if (h) {
        #pragma unroll
        for (int s4 = 0; s4 < 4; ++s4) red[s4 * PD + j] = a[s4];
    }
    __syncthreads();
    if (!h) {
        const float bp = b_p2[j];
        #pragma unroll
        for (int s4 = 0; s4 < 4; ++s4) {
            int q2 = sb * 4 + s4;
            if (q2 < 1530) {
                int b2 = q2 >= 765, k2 = q2 - 765 * b2;
                out[LOGITS_SZ + ((size_t)b2 * TOTAL + k2) * PD + j] =
                    a[s4] + red[s4 * PD + j] + bp;
            }
        }
    }
}

extern "C" void kernel_launch(void* const* d_in, const int* in_sizes, int n_in,
                              void* d_out, int out_size, void* d_ws, size_t ws_size,
                              hipStream_t stream) {
    const float* hidden    = (const float*)d_in[0];
    const float* width_emb = (const float*)d_in[1];
    const float* w_span    = (const float*)d_in[2];
    const float* b_span    = (const float*)d_in[3];
    const float* w_cls     = (const float*)d_in[4];
    const float* b_cls     = (const float*)d_in[5];
    const float* w_p1      = (const float*)d_in[6];
    const float* b_p1      = (const float*)d_in[7];
    const float* w_p2      = (const float*)d_in[8];
    const float* b_p2      = (const float*)d_in[9];
    float* out = (float*)d_out;
    float* ws  = (float*)d_ws;   // ~15.4 MB used

    k_prep<<<673, 256, 0, stream>>>(hidden, width_emb, w_span, b_span, w_cls, b_cls,
                                    w_p1, b_p1, ws);
    k_mg1<<<193, 256, 0, stream>>>(w_p2, b_p2, ws);
    k_mg2<<<237, 256, 0, stream>>>(w_cls, b_cls, ws);
    k_stage3<<<895, 256, 0, stream>>>(w_p2, b_p1, b_p2, ws, out);
}